// Round 3
// baseline (214.387 us; speedup 1.0000x reference)
//
#include <hip/hip_runtime.h>
#include <math.h>

#define DIM 1024
#define NE 4
#define NTOK 4096
#define NB 8
#define CAP 1024   // floor(0.25 * 4096)

// ===========================================================================
// probs: one wave per token. logits accumulated in double (correctly-rounded
// fp32), softmax in double, rounded once to fp32. probs layout: [(b*N+n)*4+e]
// Also zeroes the cross-block counter used by selrest (stream order makes it
// visible before selrest starts).
// ===========================================================================
__global__ __launch_bounds__(256) void probs_kernel(const float* __restrict__ tokens,
                                                    const float* __restrict__ W,
                                                    const float* __restrict__ bias,
                                                    float* __restrict__ probs,
                                                    unsigned* __restrict__ counter) {
    __shared__ float4 Wl[NE * 256];   // 16 KB
    int tid = threadIdx.x;
    if (blockIdx.x == 0 && tid == 0) counter[0] = 0u;
    const float4* W4 = (const float4*)W;
    for (int i = tid; i < NE * 256; i += 256) Wl[i] = W4[i];
    __syncthreads();

    int wave = tid >> 6, lane = tid & 63;
    long tok = (long)blockIdx.x * 4 + wave;            // 0 .. 32767
    const float4* t4 = (const float4*)(tokens + tok * DIM);

    double a0 = 0, a1 = 0, a2 = 0, a3 = 0;
#pragma unroll
    for (int kk = 0; kk < 4; kk++) {
        int c = lane + 64 * kk;                         // coalesced float4
        float4 v  = t4[c];
        float4 w0 = Wl[0 * 256 + c];
        float4 w1 = Wl[1 * 256 + c];
        float4 w2 = Wl[2 * 256 + c];
        float4 w3 = Wl[3 * 256 + c];
        a0 += (double)v.x * w0.x + (double)v.y * w0.y + (double)v.z * w0.z + (double)v.w * w0.w;
        a1 += (double)v.x * w1.x + (double)v.y * w1.y + (double)v.z * w1.z + (double)v.w * w1.w;
        a2 += (double)v.x * w2.x + (double)v.y * w2.y + (double)v.z * w2.z + (double)v.w * w2.w;
        a3 += (double)v.x * w3.x + (double)v.y * w3.y + (double)v.z * w3.z + (double)v.w * w3.w;
    }
#pragma unroll
    for (int off = 32; off > 0; off >>= 1) {
        a0 += __shfl_xor(a0, off);
        a1 += __shfl_xor(a1, off);
        a2 += __shfl_xor(a2, off);
        a3 += __shfl_xor(a3, off);
    }
    if (lane == 0) {
        float f0 = (float)(a0 + (double)bias[0]);
        float f1 = (float)(a1 + (double)bias[1]);
        float f2 = (float)(a2 + (double)bias[2]);
        float f3 = (float)(a3 + (double)bias[3]);
        double m = fmax(fmax((double)f0, (double)f1), fmax((double)f2, (double)f3));
        double e0 = exp((double)f0 - m);
        double e1 = exp((double)f1 - m);
        double e2 = exp((double)f2 - m);
        double e3 = exp((double)f3 - m);
        double s = e0 + e1 + e2 + e3;
        float4 p;
        p.x = (float)(e0 / s);
        p.y = (float)(e1 / s);
        p.z = (float)(e2 / s);
        p.w = (float)(e3 / s);
        ((float4*)probs)[tok] = p;
    }
}

// ===========================================================================
// helpers (1024-thread block)
// ===========================================================================

// exclusive prefix sum over per-thread values; wl holds >= 17 unsigneds.
// Trailing __syncthreads so wl can be reused immediately after.
__device__ __forceinline__ unsigned block_exscan_1024(unsigned v, unsigned* wl,
                                                      int tid, unsigned* total) {
    int lane = tid & 63, w = tid >> 6;    // 16 waves
    unsigned s = v;
#pragma unroll
    for (int off = 1; off < 64; off <<= 1) {
        unsigned t = __shfl_up(s, off);
        if (lane >= off) s += t;
    }
    if (lane == 63) wl[w] = s;            // wave totals
    __syncthreads();
    if (tid < 64) {
        unsigned x = (tid < 16) ? wl[tid] : 0u;
#pragma unroll
        for (int off = 1; off < 16; off <<= 1) {
            unsigned t = __shfl_up(x, off);
            if (lane >= off) x += t;
        }
        if (tid < 16) wl[tid] = x;        // inclusive wave-offset scan
    }
    __syncthreads();
    unsigned waveoff = (w == 0) ? 0u : wl[w - 1];
    unsigned tot = wl[15];
    __syncthreads();
    if (total) *total = tot;
    return waveoff + (s - v);
}

// Exact cap-th-largest over the block's 4096 register keys (4/thread),
// MSB-first 8-bit radix. Returns v* and rem (# of ==v* ties to accept by
// ascending index).
__device__ __forceinline__ void radix_select_regs(const unsigned key[4], unsigned cap,
                                                  unsigned* hist, unsigned* scanb,
                                                  unsigned* bcast, int tid,
                                                  unsigned* v_out, unsigned* rem_out) {
    if (tid == 0) { bcast[0] = 0u; bcast[1] = cap; }
    __syncthreads();
#pragma unroll
    for (int shift = 24; shift >= 0; shift -= 8) {
        if (tid < 256) hist[tid] = 0u;
        __syncthreads();
        unsigned pref = bcast[0], rem = bcast[1];
        bool all = (shift == 24);
#pragma unroll
        for (int k = 0; k < 4; k++) {
            if (all || (key[k] >> (shift + 8)) == pref)
                atomicAdd(&hist[(key[k] >> shift) & 255u], 1u);
        }
        __syncthreads();
        // wave 0: inclusive suffix scan of 256 bins via shuffles
        if (tid < 64) {
            unsigned h0 = hist[4 * tid], h1 = hist[4 * tid + 1];
            unsigned h2 = hist[4 * tid + 2], h3 = hist[4 * tid + 3];
            unsigned s3 = h3, s2 = h2 + s3, s1 = h1 + s2, s0 = h0 + s1;
            unsigned t = s0, s = t;
#pragma unroll
            for (int off = 1; off < 64; off <<= 1) {
                unsigned o = __shfl_down(s, off);
                if (tid + off < 64) s += o;
            }
            unsigned E = s - t;           // sum over lanes > tid
            scanb[4 * tid]     = E + s0;
            scanb[4 * tid + 1] = E + s1;
            scanb[4 * tid + 2] = E + s2;
            scanb[4 * tid + 3] = E + s3;
        }
        __syncthreads();
        if (tid < 256) {
            unsigned incl = scanb[tid];
            unsigned excl = (tid < 255) ? scanb[tid + 1] : 0u;
            if (excl < rem && rem <= incl) {     // exactly one digit fires
                bcast[0] = (pref << 8) | (unsigned)tid;
                bcast[1] = rem - excl;
            }
        }
        __syncthreads();
    }
    *v_out = bcast[0];
    *rem_out = bcast[1];
}

__device__ __forceinline__ unsigned mono_key(float p) {
    unsigned bits = __float_as_uint(p);
    return (bits & 0x80000000u) ? ~bits : (bits | 0x80000000u);
}

// top-CAP of the block's register keys -> LDS bitmap (lax.top_k tie-break:
// lowest index wins). Thread t owns ascending indices 4t..4t+3.
__device__ __forceinline__ void select_to_bitmap(const unsigned key[4], unsigned* bitmap,
                                                 unsigned* hist, unsigned* scanb,
                                                 unsigned* bcast, unsigned* wl, int tid) {
    unsigned vstar, rem;
    radix_select_regs(key, CAP, hist, scanb, bcast, tid, &vstar, &rem);
    unsigned loc[4], v = 0;
#pragma unroll
    for (int k = 0; k < 4; k++) { loc[k] = (key[k] == vstar); v += loc[k]; }
    unsigned tot;
    unsigned ex = block_exscan_1024(v, wl, tid, &tot);
#pragma unroll
    for (int k = 0; k < 4; k++) {
        int i = 4 * tid + k;
        bool sel = (key[k] > vstar) || (loc[k] && ex < rem);
        ex += loc[k];
        if (sel) atomicOr(&bitmap[i >> 5], 1u << (i & 31));
    }
    __syncthreads();
}

// ===========================================================================
// selrest: 8 blocks, one per batch row. Each block: exact top-CAP of expert-3
// probs (register radix select) -> bitmap -> global selbits (device-scope
// atomics). Last block to finish unions the 8 bitmaps (mask=3) and runs
// rounds j=2,1,0. Mask is row-shared => unmasked count U is row-independent:
//   U <= CAP : every row selects ALL unmasked + (CAP-U) lowest-index masked
//              (-inf ties, lax.top_k stable order) -> one block scan.
//   U >  CAP : general fallback: per-row radix select among unmasked, union.
// Writes final token_mask (-1 -> 0).
// ===========================================================================
__global__ __launch_bounds__(1024) void selrest_kernel(const float* __restrict__ probs,
                                                       unsigned* __restrict__ selbits,
                                                       unsigned* __restrict__ counter,
                                                       int* __restrict__ finalmask) {
    __shared__ int maskv[NTOK];               // 16 KB (last block only)
    __shared__ unsigned hist[256], scanb[256], bcast[2];
    __shared__ unsigned bitmap[128];
    __shared__ unsigned wl[17];
    __shared__ int islast;
    int b = blockIdx.x, tid = threadIdx.x;

    // --- per-row top-CAP for expert 3, keys in registers ---
    const float4* p4 = (const float4*)probs + (size_t)b * NTOK;
    unsigned key[4];
#pragma unroll
    for (int k = 0; k < 4; k++) key[k] = mono_key(p4[4 * tid + k].w);   // expert 3
    if (tid < 128) bitmap[tid] = 0u;
    __syncthreads();

    select_to_bitmap(key, bitmap, hist, scanb, bcast, wl, tid);

    if (tid < 128) atomicExch(&selbits[b * 128 + tid], bitmap[tid]);    // device-scope
    __threadfence();                       // release bitmap before counter bump
    __syncthreads();
    if (tid == 0) islast = (atomicAdd(counter, 1u) == NB - 1);
    __syncthreads();
    if (!islast) return;

    // --- last block: union -> mask=3, then rounds j=2,1,0 ---
    __threadfence();                       // acquire
    if (tid < 128) {
        unsigned u = 0;
#pragma unroll
        for (int bb = 0; bb < NB; bb++) u |= atomicOr(&selbits[bb * 128 + tid], 0u);
        bitmap[tid] = u;
    }
    __syncthreads();
#pragma unroll
    for (int k = 0; k < 4; k++) {
        int i = tid + k * 1024;
        maskv[i] = ((bitmap[i >> 5] >> (i & 31)) & 1u) ? 3 : -1;
    }
    __syncthreads();

    for (int j = 2; j >= 0; j--) {
        unsigned loc[4], v = 0;
#pragma unroll
        for (int k = 0; k < 4; k++) { loc[k] = (maskv[4 * tid + k] != -1); v += loc[k]; }
        unsigned M;
        unsigned ex = block_exscan_1024(v, wl, tid, &M);
        unsigned U = NTOK - M;

        if (U <= CAP) {
            unsigned need = CAP - U;       // -inf ties to take (lowest index)
#pragma unroll
            for (int k = 0; k < 4; k++) {
                int i = 4 * tid + k;
                bool sel = (!loc[k]) || (ex < need);
                ex += loc[k];
                if (sel) maskv[i] = j;     // thread owns its 4 indices
            }
            __syncthreads();
        } else {
            // general fallback (not expected on this data)
            if (tid < 128) bitmap[tid] = 0u;
            __syncthreads();
            for (int bb = 0; bb < NB; bb++) {
                unsigned k2[4];
#pragma unroll
                for (int k = 0; k < 4; k++) {
                    int i = 4 * tid + k;
                    k2[k] = (maskv[i] != -1)
                                ? 0u   // below every real prob key (>= 0x80000000)
                                : mono_key(probs[((size_t)bb * NTOK + i) * NE + j]);
                }
                select_to_bitmap(k2, bitmap, hist, scanb, bcast, wl, tid);
            }
#pragma unroll
            for (int k = 0; k < 4; k++) {
                int i = 4 * tid + k;
                if ((bitmap[i >> 5] >> (i & 31)) & 1u) maskv[i] = j;
            }
            __syncthreads();
        }
    }

#pragma unroll
    for (int k = 0; k < 4; k++) {
        int i = tid + k * 1024;
        int m = maskv[i];
        finalmask[i] = (m < 0) ? 0 : m;
    }
}

// ===========================================================================
// final: out[0..B*N) = (float)mask broadcast; out[B*N..2*B*N) = gathered probs
// ===========================================================================
__global__ __launch_bounds__(256) void final_kernel(const float* __restrict__ probs,
                                                    const int* __restrict__ fm,
                                                    float* __restrict__ out) {
    int i = blockIdx.x * 256 + threadIdx.x;   // 0 .. B*N-1
    int n = i & (NTOK - 1);
    int m = fm[n];
    out[i] = (float)m;
    out[NB * NTOK + i] = probs[(size_t)i * NE + m];
}

extern "C" void kernel_launch(void* const* d_in, const int* in_sizes, int n_in,
                              void* d_out, int out_size, void* d_ws, size_t ws_size,
                              hipStream_t stream) {
    const float* tokens = (const float*)d_in[0];   // [8, 4096, 1024] fp32
    const float* W      = (const float*)d_in[1];   // [4, 1024] fp32
    const float* bias   = (const float*)d_in[2];   // [4] fp32
    float* out = (float*)d_out;                    // [2 * 8 * 4096] fp32

    float*    probs   = (float*)d_ws;                                   // 512 KB
    unsigned* selbits = (unsigned*)((char*)d_ws + (size_t)NB * NTOK * NE * sizeof(float));
    int*      fmask   = (int*)(selbits + NB * 128);                     // 16 KB
    unsigned* counter = (unsigned*)(fmask + NTOK);

    probs_kernel<<<(NB * NTOK) / 4, 256, 0, stream>>>(tokens, W, bias, probs, counter);
    selrest_kernel<<<NB, 1024, 0, stream>>>(probs, selbits, counter, fmask);
    final_kernel<<<(NB * NTOK) / 256, 256, 0, stream>>>(probs, fmask, out);
}

// Round 5
// 211.411 us; speedup vs baseline: 1.0141x; 1.0141x over previous
//
#include <hip/hip_runtime.h>
#include <math.h>

#define DIM 1024
#define NE 4
#define NTOK 4096
#define NB 8
#define CAP 1024     // floor(0.25 * 4096)
#define NWAVE 16     // 1024-thread blocks
#define HSTRIDE 257  // per-wave histogram stride: rotates banks per wave

typedef float fx4 __attribute__((ext_vector_type(4)));   // NT-loadable float4

// ===========================================================================
// probs: one wave per token. logits accumulated in double (correctly-rounded
// fp32), softmax in double, rounded once to fp32. probs layout: [(b*N+n)*4+e]
// Numerics unchanged since round 1 (token_mask matched exactly).
// Non-temporal token loads: 134 MB streams once (>> L2), no reuse.
// ===========================================================================
__global__ __launch_bounds__(256) void probs_kernel(const float* __restrict__ tokens,
                                                    const float* __restrict__ W,
                                                    const float* __restrict__ bias,
                                                    float* __restrict__ probs) {
    __shared__ float4 Wl[NE * 256];   // 16 KB
    int tid = threadIdx.x;
    const float4* W4 = (const float4*)W;
    for (int i = tid; i < NE * 256; i += 256) Wl[i] = W4[i];
    __syncthreads();

    int wave = tid >> 6, lane = tid & 63;
    long tok = (long)blockIdx.x * 4 + wave;            // 0 .. 32767
    const fx4* t4 = (const fx4*)(tokens + tok * DIM);

    double a0 = 0, a1 = 0, a2 = 0, a3 = 0;
#pragma unroll
    for (int kk = 0; kk < 4; kk++) {
        int c = lane + 64 * kk;                         // coalesced 16B
        fx4 v = __builtin_nontemporal_load(&t4[c]);
        float4 w0 = Wl[0 * 256 + c];
        float4 w1 = Wl[1 * 256 + c];
        float4 w2 = Wl[2 * 256 + c];
        float4 w3 = Wl[3 * 256 + c];
        a0 += (double)v.x * w0.x + (double)v.y * w0.y + (double)v.z * w0.z + (double)v.w * w0.w;
        a1 += (double)v.x * w1.x + (double)v.y * w1.y + (double)v.z * w1.z + (double)v.w * w1.w;
        a2 += (double)v.x * w2.x + (double)v.y * w2.y + (double)v.z * w2.z + (double)v.w * w2.w;
        a3 += (double)v.x * w3.x + (double)v.y * w3.y + (double)v.z * w3.z + (double)v.w * w3.w;
    }
#pragma unroll
    for (int off = 32; off > 0; off >>= 1) {
        a0 += __shfl_xor(a0, off);
        a1 += __shfl_xor(a1, off);
        a2 += __shfl_xor(a2, off);
        a3 += __shfl_xor(a3, off);
    }
    if (lane == 0) {
        float f0 = (float)(a0 + (double)bias[0]);
        float f1 = (float)(a1 + (double)bias[1]);
        float f2 = (float)(a2 + (double)bias[2]);
        float f3 = (float)(a3 + (double)bias[3]);
        double m = fmax(fmax((double)f0, (double)f1), fmax((double)f2, (double)f3));
        double e0 = exp((double)f0 - m);
        double e1 = exp((double)f1 - m);
        double e2 = exp((double)f2 - m);
        double e3 = exp((double)f3 - m);
        double s = e0 + e1 + e2 + e3;
        float4 p;
        p.x = (float)(e0 / s);
        p.y = (float)(e1 / s);
        p.z = (float)(e2 / s);
        p.w = (float)(e3 / s);
        ((float4*)probs)[tok] = p;
    }
}

// ===========================================================================
// helpers (1024-thread block)
// ===========================================================================

// exclusive prefix sum over per-thread values; wl holds >= 17 unsigneds.
// Trailing __syncthreads so wl can be reused immediately after.
__device__ __forceinline__ unsigned block_exscan_1024(unsigned v, unsigned* wl,
                                                      int tid, unsigned* total) {
    int lane = tid & 63, w = tid >> 6;    // 16 waves
    unsigned s = v;
#pragma unroll
    for (int off = 1; off < 64; off <<= 1) {
        unsigned t = __shfl_up(s, off);
        if (lane >= off) s += t;
    }
    if (lane == 63) wl[w] = s;            // wave totals
    __syncthreads();
    if (tid < 64) {
        unsigned x = (tid < 16) ? wl[tid] : 0u;
#pragma unroll
        for (int off = 1; off < 16; off <<= 1) {
            unsigned t = __shfl_up(x, off);
            if (lane >= off) x += t;
        }
        if (tid < 16) wl[tid] = x;        // inclusive wave-offset scan
    }
    __syncthreads();
    unsigned waveoff = (w == 0) ? 0u : wl[w - 1];
    unsigned tot = wl[15];
    __syncthreads();
    if (total) *total = tot;
    return waveoff + (s - v);
}

// Exact cap-th-largest over the block's 4096 register keys (4/thread),
// MSB-first 8-bit radix with PER-WAVE histograms (stride 257 -> each wave's
// bins on rotated banks; no cross-wave LDS-atomic serialization even when
// softmax probs concentrate in a few exponent bins). Returns v* and rem
// (# of ==v* ties to accept by ascending index).
__device__ __forceinline__ void radix_select_regs(const unsigned key[4], unsigned cap,
                                                  unsigned* whist, unsigned* hist,
                                                  unsigned* scanb, unsigned* bcast,
                                                  int tid,
                                                  unsigned* v_out, unsigned* rem_out) {
    int w = tid >> 6;
    unsigned* myh = whist + w * HSTRIDE;
    if (tid == 0) { bcast[0] = 0u; bcast[1] = cap; }
#pragma unroll
    for (int shift = 24; shift >= 0; shift -= 8) {
        for (int i = tid; i < NWAVE * HSTRIDE; i += 1024) whist[i] = 0u;
        __syncthreads();
        unsigned pref = bcast[0], rem = bcast[1];
        bool all = (shift == 24);
#pragma unroll
        for (int k = 0; k < 4; k++) {
            if (all || (key[k] >> (shift + 8)) == pref)
                atomicAdd(&myh[(key[k] >> shift) & 255u], 1u);
        }
        __syncthreads();
        if (tid < 256) {                  // sum the 16 wave-histograms
            unsigned s = 0;
#pragma unroll
            for (int w2 = 0; w2 < NWAVE; w2++) s += whist[w2 * HSTRIDE + tid];
            hist[tid] = s;
        }
        __syncthreads();
        // wave 0: inclusive suffix scan of 256 bins via shuffles
        if (tid < 64) {
            unsigned h0 = hist[4 * tid], h1 = hist[4 * tid + 1];
            unsigned h2 = hist[4 * tid + 2], h3 = hist[4 * tid + 3];
            unsigned s3 = h3, s2 = h2 + s3, s1 = h1 + s2, s0 = h0 + s1;
            unsigned t = s0, s = t;
#pragma unroll
            for (int off = 1; off < 64; off <<= 1) {
                unsigned o = __shfl_down(s, off);
                if (tid + off < 64) s += o;
            }
            unsigned E = s - t;           // sum over lanes > tid
            scanb[4 * tid]     = E + s0;
            scanb[4 * tid + 1] = E + s1;
            scanb[4 * tid + 2] = E + s2;
            scanb[4 * tid + 3] = E + s3;
        }
        __syncthreads();
        if (tid < 256) {
            unsigned incl = scanb[tid];
            unsigned excl = (tid < 255) ? scanb[tid + 1] : 0u;
            if (excl < rem && rem <= incl) {     // exactly one digit fires
                bcast[0] = (pref << 8) | (unsigned)tid;
                bcast[1] = rem - excl;
            }
        }
        __syncthreads();
    }
    *v_out = bcast[0];
    *rem_out = bcast[1];
}

__device__ __forceinline__ unsigned mono_key(float p) {
    unsigned bits = __float_as_uint(p);
    return (bits & 0x80000000u) ? ~bits : (bits | 0x80000000u);
}

// top-CAP of the block's register keys -> LDS bitmap (lax.top_k tie-break:
// lowest index wins). Thread t owns ascending indices 4t..4t+3.
__device__ __forceinline__ void select_to_bitmap(const unsigned key[4], unsigned* bitmap,
                                                 unsigned* whist, unsigned* hist,
                                                 unsigned* scanb, unsigned* bcast,
                                                 unsigned* wl, int tid) {
    unsigned vstar, rem;
    radix_select_regs(key, CAP, whist, hist, scanb, bcast, tid, &vstar, &rem);
    unsigned loc[4], v = 0;
#pragma unroll
    for (int k = 0; k < 4; k++) { loc[k] = (key[k] == vstar); v += loc[k]; }
    unsigned tot;
    unsigned ex = block_exscan_1024(v, wl, tid, &tot);
#pragma unroll
    for (int k = 0; k < 4; k++) {
        int i = 4 * tid + k;
        bool sel = (key[k] > vstar) || (loc[k] && ex < rem);
        ex += loc[k];
        if (sel) atomicOr(&bitmap[i >> 5], 1u << (i & 31));
    }
    __syncthreads();
}

// ===========================================================================
// select3: round j=3 (no mask yet). One block per batch row. Exact top-CAP
// of expert-3 probs -> bitmap -> selbits (plain stores; cross-kernel
// visibility is guaranteed at launch boundaries).
// ===========================================================================
__global__ __launch_bounds__(1024) void select3_kernel(const float* __restrict__ probs,
                                                       unsigned* __restrict__ selbits) {
    __shared__ unsigned whist[NWAVE * HSTRIDE];   // 16.4 KB
    __shared__ unsigned hist[256], scanb[256], bcast[2];
    __shared__ unsigned bitmap[128];
    __shared__ unsigned wl[17];
    int b = blockIdx.x, tid = threadIdx.x;

    const float4* p4 = (const float4*)probs + (size_t)b * NTOK;
    unsigned key[4];
#pragma unroll
    for (int k = 0; k < 4; k++) key[k] = mono_key(p4[4 * tid + k].w);   // expert 3
    if (tid < 128) bitmap[tid] = 0u;
    // first barrier happens inside radix_select_regs (after hist clear)

    select_to_bitmap(key, bitmap, whist, hist, scanb, bcast, wl, tid);

    if (tid < 128) selbits[b * 128 + tid] = bitmap[tid];
}

// ===========================================================================
// rest: single block. Union round-3 bitmaps -> mask=3; then rounds j=2,1,0.
// Mask is row-shared => unmasked count U is row-independent:
//   U <= CAP : every row selects ALL unmasked + (CAP-U) lowest-index masked
//              (-inf ties, lax.top_k stable order) -> one block scan, no topk.
//   U >  CAP : general fallback: per-row radix select among unmasked, union.
// Writes final token_mask (-1 -> 0).
// ===========================================================================
__global__ __launch_bounds__(1024) void rest_kernel(const float* __restrict__ probs,
                                                    const unsigned* __restrict__ selbits,
                                                    int* __restrict__ finalmask) {
    __shared__ int maskv[NTOK];                   // 16 KB
    __shared__ unsigned whist[NWAVE * HSTRIDE];   // 16.4 KB (fallback only)
    __shared__ unsigned hist[256], scanb[256], bcast[2];
    __shared__ unsigned bitmap[128];
    __shared__ unsigned wl[17];
    int tid = threadIdx.x;

    if (tid < 128) {
        unsigned u = 0;
#pragma unroll
        for (int bb = 0; bb < NB; bb++) u |= selbits[bb * 128 + tid];
        bitmap[tid] = u;
    }
    __syncthreads();
#pragma unroll
    for (int k = 0; k < 4; k++) {
        int i = tid + k * 1024;
        maskv[i] = ((bitmap[i >> 5] >> (i & 31)) & 1u) ? 3 : -1;
    }
    __syncthreads();

    for (int j = 2; j >= 0; j--) {
        unsigned loc[4], v = 0;
#pragma unroll
        for (int k = 0; k < 4; k++) { loc[k] = (maskv[4 * tid + k] != -1); v += loc[k]; }
        unsigned M;
        unsigned ex = block_exscan_1024(v, wl, tid, &M);
        unsigned U = NTOK - M;

        if (U <= CAP) {
            unsigned need = CAP - U;       // -inf ties to take (lowest index)
#pragma unroll
            for (int k = 0; k < 4; k++) {
                int i = 4 * tid + k;
                bool sel = (!loc[k]) || (ex < need);
                ex += loc[k];
                if (sel) maskv[i] = j;     // thread owns its 4 indices
            }
            __syncthreads();
        } else {
            // general fallback (not expected on this data, but exact)
            if (tid < 128) bitmap[tid] = 0u;
            __syncthreads();
            for (int bb = 0; bb < NB; bb++) {
                unsigned k2[4];
#pragma unroll
                for (int k = 0; k < 4; k++) {
                    int i = 4 * tid + k;
                    k2[k] = (maskv[i] != -1)
                                ? 0u   // below every real prob key (>= 0x80000000)
                                : mono_key(probs[((size_t)bb * NTOK + i) * NE + j]);
                }
                select_to_bitmap(k2, bitmap, whist, hist, scanb, bcast, wl, tid);
            }
#pragma unroll
            for (int k = 0; k < 4; k++) {
                int i = 4 * tid + k;
                if ((bitmap[i >> 5] >> (i & 31)) & 1u) maskv[i] = j;
            }
            __syncthreads();
        }
    }

#pragma unroll
    for (int k = 0; k < 4; k++) {
        int i = tid + k * 1024;
        int m = maskv[i];
        finalmask[i] = (m < 0) ? 0 : m;
    }
}

// ===========================================================================
// final: out[0..B*N) = (float)mask broadcast; out[B*N..2*B*N) = gathered probs
// ===========================================================================
__global__ __launch_bounds__(256) void final_kernel(const float* __restrict__ probs,
                                                    const int* __restrict__ fm,
                                                    float* __restrict__ out) {
    int i = blockIdx.x * 256 + threadIdx.x;   // 0 .. B*N-1
    int n = i & (NTOK - 1);
    int m = fm[n];
    out[i] = (float)m;
    out[NB * NTOK + i] = probs[(size_t)i * NE + m];
}

extern "C" void kernel_launch(void* const* d_in, const int* in_sizes, int n_in,
                              void* d_out, int out_size, void* d_ws, size_t ws_size,
                              hipStream_t stream) {
    const float* tokens = (const float*)d_in[0];   // [8, 4096, 1024] fp32
    const float* W      = (const float*)d_in[1];   // [4, 1024] fp32
    const float* bias   = (const float*)d_in[2];   // [4] fp32
    float* out = (float*)d_out;                    // [2 * 8 * 4096] fp32

    float*    probs   = (float*)d_ws;                                   // 512 KB
    unsigned* selbits = (unsigned*)((char*)d_ws + (size_t)NB * NTOK * NE * sizeof(float));
    int*      fmask   = (int*)(selbits + NB * 128);                     // 16 KB

    probs_kernel<<<(NB * NTOK) / 4, 256, 0, stream>>>(tokens, W, bias, probs);
    select3_kernel<<<NB, 1024, 0, stream>>>(probs, selbits);
    rest_kernel<<<1, 1024, 0, stream>>>(probs, selbits, fmask);
    final_kernel<<<(NB * NTOK) / 256, 256, 0, stream>>>(probs, fmask, out);
}